// Round 1
// baseline (477.928 us; speedup 1.0000x reference)
//
#include <hip/hip_runtime.h>

// ClusteringLayer: q[n,k] = (1/(1+dist2))^((a+1)/2) / rowsum, a=1 -> exponent 1
// dist2 = ||x||^2 + ||c||^2 - 2 x.c  (clamped at 0)
// N=200000, D=128, K=256, fp32 in/out.
//
// Round 0: fp32 VALU tiled kernel, fused normalization.
// Block = 256 threads, owns TM=64 rows x all 256 cols.
// Per-thread micro-tile: 4 rows x 16 cols (cols stride-16 to keep LDS
// b128 c-reads at 2-way bank aliasing, which is free on gfx950).

#define DIM   128
#define NK    256
#define TM    64
#define BLOCK 256
#define LDP   132   // padded leading dim (floats), multiple of 4 for b128

__global__ __launch_bounds__(BLOCK, 2) void cluster_q_kernel(
    const float* __restrict__ x,    // [N, DIM]
    const float* __restrict__ c,    // [NK, DIM]
    float* __restrict__ out,        // [N, NK]
    int N)
{
    __shared__ float xs[TM][LDP];
    __shared__ float cs[TM][LDP];
    __shared__ float xsq_s[TM];
    __shared__ float csq_s[NK];
    __shared__ float psum[TM][16];

    const int tid = threadIdx.x;
    const int tc  = tid & 15;   // col group 0..15
    const int tr  = tid >> 4;   // row group 0..15 (4 rows each)
    const size_t row0 = (size_t)blockIdx.x * TM;

    // ---- stage x tile: 64 rows x 128 d = 2048 float4, 8 per thread ----
    {
        const float4* xg = (const float4*)(x + row0 * DIM);
        #pragma unroll
        for (int it = 0; it < 8; ++it) {
            int l  = tid + BLOCK * it;     // float4 index, contiguous
            int r  = l >> 5;               // DIM/4 = 32 float4 per row
            int d4 = l & 31;
            *(float4*)&xs[r][d4 * 4] = xg[l];
        }
    }

    // ---- c_sq for all 256 clusters: thread t handles cluster t ----
    {
        const float4* cg = (const float4*)(c + (size_t)tid * DIM);
        float s = 0.f;
        #pragma unroll 8
        for (int d4 = 0; d4 < 32; ++d4) {
            float4 v = cg[d4];
            s = fmaf(v.x, v.x, s); s = fmaf(v.y, v.y, s);
            s = fmaf(v.z, v.z, s); s = fmaf(v.w, v.w, s);
        }
        csq_s[tid] = s;
    }
    __syncthreads();

    // ---- x_sq from staged tile (wave 0) ----
    if (tid < TM) {
        float s = 0.f;
        #pragma unroll 8
        for (int d4 = 0; d4 < 32; ++d4) {
            float4 v = *(const float4*)&xs[tid][d4 * 4];
            s = fmaf(v.x, v.x, s); s = fmaf(v.y, v.y, s);
            s = fmaf(v.z, v.z, s); s = fmaf(v.w, v.w, s);
        }
        xsq_s[tid] = s;
    }

    float acc[4][16];
    #pragma unroll
    for (int i = 0; i < 4; ++i)
        #pragma unroll
        for (int j = 0; j < 16; ++j) acc[i][j] = 0.f;

    // ---- main loop: 4 chunks of 64 cluster cols ----
    for (int kc = 0; kc < 4; ++kc) {
        __syncthreads();   // previous chunk's compute done with cs
        {
            const float4* cg = (const float4*)(c + (size_t)kc * TM * DIM);
            #pragma unroll
            for (int it = 0; it < 8; ++it) {
                int l  = tid + BLOCK * it;
                int r  = l >> 5;
                int d4 = l & 31;
                *(float4*)&cs[r][d4 * 4] = cg[l];
            }
        }
        __syncthreads();

        for (int d = 0; d < DIM; d += 4) {
            float4 xv[4], cv[4];
            #pragma unroll
            for (int i = 0; i < 4; ++i)
                xv[i] = *(const float4*)&xs[tr * 4 + i][d];
            #pragma unroll
            for (int j = 0; j < 4; ++j)
                cv[j] = *(const float4*)&cs[16 * j + tc][d];   // stride-16 cols
            #pragma unroll
            for (int i = 0; i < 4; ++i) {
                #pragma unroll
                for (int j = 0; j < 4; ++j) {
                    float a = acc[i][kc * 4 + j];
                    a = fmaf(xv[i].x, cv[j].x, a);
                    a = fmaf(xv[i].y, cv[j].y, a);
                    a = fmaf(xv[i].z, cv[j].z, a);
                    a = fmaf(xv[i].w, cv[j].w, a);
                    acc[i][kc * 4 + j] = a;
                }
            }
        }
    }

    // ---- epilogue: q_raw, row partial sums ----
    #pragma unroll
    for (int i = 0; i < 4; ++i) {
        int r = tr * 4 + i;
        float xq = xsq_s[r];
        float s = 0.f;
        #pragma unroll
        for (int kc = 0; kc < 4; ++kc) {
            #pragma unroll
            for (int j = 0; j < 4; ++j) {
                int k = kc * 64 + 16 * j + tc;
                float d2 = fmaxf(xq + csq_s[k] - 2.f * acc[i][kc * 4 + j], 0.f);
                float q = 1.f / (1.f + d2);
                acc[i][kc * 4 + j] = q;
                s += q;
            }
        }
        psum[r][tc] = s;
    }
    __syncthreads();

    // ---- normalize + store (coalesced-ish: lanes tc are adjacent floats) ----
    #pragma unroll
    for (int i = 0; i < 4; ++i) {
        int r = tr * 4 + i;
        float S = 0.f;
        #pragma unroll
        for (int t = 0; t < 16; ++t) S += psum[r][t];
        float inv = 1.f / S;
        size_t base = (row0 + r) * NK;
        #pragma unroll
        for (int kc = 0; kc < 4; ++kc) {
            #pragma unroll
            for (int j = 0; j < 4; ++j) {
                out[base + kc * 64 + 16 * j + tc] = acc[i][kc * 4 + j] * inv;
            }
        }
    }
}

extern "C" void kernel_launch(void* const* d_in, const int* in_sizes, int n_in,
                              void* d_out, int out_size, void* d_ws, size_t ws_size,
                              hipStream_t stream) {
    const float* x = (const float*)d_in[0];   // [N, 128] fp32
    const float* c = (const float*)d_in[1];   // [256, 128] fp32
    float* out = (float*)d_out;               // [N, 256] fp32
    int N = in_sizes[0] / DIM;                // 200000 (divisible by TM=64)
    dim3 grid(N / TM);
    cluster_q_kernel<<<grid, BLOCK, 0, stream>>>(x, c, out, N);
}

// Round 2
// 330.758 us; speedup vs baseline: 1.4449x; 1.4449x over previous
//
#include <hip/hip_runtime.h>

// ClusteringLayer on gfx950: q = softmax-like normalize of 1/(1+dist2).
// dist2 = xsq + csq - 2 x.c  (exact fp32 xsq/csq; cross via bf16 MFMA with
// one-sided split x = x_hi + x_lo  => 2 MFMA passes, error ~1e-5).
// Block: 512 thr = 8 waves, 64 rows x 256 cols. Wave w: 64 rows x cols [32w,32w+32).
// B (clusters) fragments live in VGPRs (loaded once per block from L2-resident C);
// K-loop reads only A (x-tile hi/lo) from LDS. No barriers in K-loop.

#define DIM 128
#define NK  256
#define TM  64
#define THREADS 512
#define LSTR 136   // ushort elems per LDS row: 272B = 16B-aligned rows, 8-pass b128

typedef __attribute__((ext_vector_type(8))) short short8;
typedef __attribute__((ext_vector_type(4))) float floatx4;

__device__ __forceinline__ unsigned short bf16_rne(float f) {
    unsigned int u = __float_as_uint(f);
    return (unsigned short)((u + 0x7fffu + ((u >> 16) & 1u)) >> 16);
}
__device__ __forceinline__ float bf16_f(unsigned short h) {
    return __uint_as_float(((unsigned int)h) << 16);
}

__global__ __launch_bounds__(THREADS, 4) void cluster_q_mfma(
    const float* __restrict__ x,
    const float* __restrict__ c,
    float* __restrict__ out)
{
    __shared__ __align__(16) unsigned short xs_hi[TM][LSTR];
    __shared__ __align__(16) unsigned short xs_lo[TM][LSTR];
    __shared__ float xsq_s[TM];
    __shared__ float psum[TM][8];
    __shared__ float inv_s[TM];

    const int tid  = threadIdx.x;
    const int wave = tid >> 6;
    const int lane = tid & 63;
    const int lm   = lane & 15;   // MFMA row (A) / col (B,C) within tile
    const int q4   = lane >> 4;   // quad
    const size_t row0 = (size_t)blockIdx.x * TM;

    // ---- stage X tile: thread t -> row t>>3, 16 cols at (t&7)*16 ----
    {
        const int r  = tid >> 3;
        const int cb = (tid & 7) * 16;
        const float4* xg = (const float4*)(x + (row0 + r) * DIM + cb);
        float4 f4[4];
        #pragma unroll
        for (int i = 0; i < 4; ++i) f4[i] = xg[i];
        const float* fv = (const float*)f4;
        union { unsigned short u[16]; short8 v[2]; } H, L;
        float s = 0.f;
        #pragma unroll
        for (int i = 0; i < 16; ++i) {
            float f = fv[i];
            s = fmaf(f, f, s);
            unsigned short h = bf16_rne(f);
            H.u[i] = h;
            L.u[i] = bf16_rne(f - bf16_f(h));
        }
        *(short8*)&xs_hi[r][cb]     = H.v[0];
        *(short8*)&xs_hi[r][cb + 8] = H.v[1];
        *(short8*)&xs_lo[r][cb]     = L.v[0];
        *(short8*)&xs_lo[r][cb + 8] = L.v[1];
        // exact fp32 row-norm: reduce over the 8 threads of this row
        s += __shfl_xor(s, 1);
        s += __shfl_xor(s, 2);
        s += __shfl_xor(s, 4);
        if ((tid & 7) == 0) xsq_s[r] = s;
    }

    // ---- B fragments (this wave's 32 cols) in registers + exact fp32 csq ----
    // B layout for 16x16x32: lane holds B[k = ks*32 + q4*8 + j][col = lm]
    short8 bf[2][4];
    float csq[2];
    #pragma unroll
    for (int ct = 0; ct < 2; ++ct) {
        float cp = 0.f;
        const int col = wave * 32 + ct * 16 + lm;
        #pragma unroll
        for (int ks = 0; ks < 4; ++ks) {
            const float4* cg = (const float4*)(c + col * DIM + ks * 32 + q4 * 8);
            float4 b0 = cg[0], b1 = cg[1];
            const float* bv0 = (const float*)&b0;
            const float* bv1 = (const float*)&b1;
            union { unsigned short u[8]; short8 v; } B;
            #pragma unroll
            for (int i = 0; i < 4; ++i) {
                float f = bv0[i];
                cp = fmaf(f, f, cp);
                B.u[i] = bf16_rne(f);
            }
            #pragma unroll
            for (int i = 0; i < 4; ++i) {
                float f = bv1[i];
                cp = fmaf(f, f, cp);
                B.u[4 + i] = bf16_rne(f);
            }
            bf[ct][ks] = B.v;
        }
        // lane covers quarter of k per col; partner quads hold the rest
        cp += __shfl_xor(cp, 16);
        cp += __shfl_xor(cp, 32);
        csq[ct] = cp;
    }

    floatx4 acc[4][2];
    #pragma unroll
    for (int rt = 0; rt < 4; ++rt)
        #pragma unroll
        for (int ct = 0; ct < 2; ++ct)
            acc[rt][ct] = (floatx4){0.f, 0.f, 0.f, 0.f};

    __syncthreads();

    // ---- K loop: A from LDS, B from regs, 2 passes (hi, lo) ----
    #pragma unroll
    for (int ks = 0; ks < 4; ++ks) {
        const int ko = ks * 32 + q4 * 8;
        #pragma unroll
        for (int rt = 0; rt < 4; ++rt) {
            short8 ah = *(const short8*)&xs_hi[rt * 16 + lm][ko];
            short8 al = *(const short8*)&xs_lo[rt * 16 + lm][ko];
            #pragma unroll
            for (int ct = 0; ct < 2; ++ct) {
                acc[rt][ct] = __builtin_amdgcn_mfma_f32_16x16x32_bf16(ah, bf[ct][ks], acc[rt][ct], 0, 0, 0);
                acc[rt][ct] = __builtin_amdgcn_mfma_f32_16x16x32_bf16(al, bf[ct][ks], acc[rt][ct], 0, 0, 0);
            }
        }
    }

    // ---- epilogue: q = 1/(1+dist2), per-row partial sums ----
    #pragma unroll
    for (int rt = 0; rt < 4; ++rt) {
        #pragma unroll
        for (int reg = 0; reg < 4; ++reg) {
            const int r = rt * 16 + q4 * 4 + reg;   // C/D row
            const float xq = xsq_s[r];
            float p = 0.f;
            #pragma unroll
            for (int ct = 0; ct < 2; ++ct) {
                float d2 = xq + csq[ct] - 2.f * acc[rt][ct][reg];
                d2 = fmaxf(d2, 0.f);
                float q = 1.f / (1.f + d2);
                acc[rt][ct][reg] = q;
                p += q;
            }
            // sum over the 16 col-lanes of this quad-row
            p += __shfl_xor(p, 1);
            p += __shfl_xor(p, 2);
            p += __shfl_xor(p, 4);
            p += __shfl_xor(p, 8);
            if (lm == 0) psum[r][wave] = p;
        }
    }
    __syncthreads();

    if (tid < TM) {
        float s = 0.f;
        #pragma unroll
        for (int w = 0; w < 8; ++w) s += psum[tid][w];
        inv_s[tid] = 1.f / s;
    }
    __syncthreads();

    // ---- normalize + store ----
    #pragma unroll
    for (int rt = 0; rt < 4; ++rt) {
        #pragma unroll
        for (int reg = 0; reg < 4; ++reg) {
            const int r = rt * 16 + q4 * 4 + reg;
            const float inv = inv_s[r];
            #pragma unroll
            for (int ct = 0; ct < 2; ++ct) {
                out[(row0 + r) * NK + wave * 32 + ct * 16 + lm] = acc[rt][ct][reg] * inv;
            }
        }
    }
}

extern "C" void kernel_launch(void* const* d_in, const int* in_sizes, int n_in,
                              void* d_out, int out_size, void* d_ws, size_t ws_size,
                              hipStream_t stream) {
    const float* x = (const float*)d_in[0];   // [200000, 128] fp32
    const float* c = (const float*)d_in[1];   // [256, 128] fp32
    float* out = (float*)d_out;               // [200000, 256] fp32
    int N = in_sizes[0] / DIM;                // 200000 = 3125 * 64
    cluster_q_mfma<<<dim3(N / TM), dim3(THREADS), 0, stream>>>(x, c, out);
}